// Round 18
// baseline (88.181 us; speedup 1.0000x reference)
//
#include <hip/hip_runtime.h>
#include <hip/hip_bf16.h>

#define N_NODES 4096
#define F_IN    128
#define HEADS   4
#define FTOT    128
#define NSPLIT  8
#define NRANGE  (N_NODES / NSPLIT)   // 512
#define NSTEP   (NRANGE / 64)        // 8
#define HPB     512
#define BITB    1024
#define L2E     1.4426950408889634f

typedef __attribute__((ext_vector_type(8)))  short  short8v;
typedef __attribute__((ext_vector_type(16))) float  float16v;

static __device__ __forceinline__ unsigned f2bfu(float f) {
    union { __hip_bfloat16 h; unsigned short u; } cv;
    cv.h = __float2bfloat16(f);
    return (unsigned)cv.u;
}
static __device__ __forceinline__ unsigned cvt_pk_bf16(float lo, float hi) {
    unsigned r;
    asm("v_cvt_pk_bf16_f32 %0, %1, %2" : "=v"(r) : "v"(lo), "v"(hi));
    return r;
}

// hpt tiled layout: element (f, n) lives at ((n>>4)*128 + f)*16 + (n&15).
// A wave's B-fragment read is then 1KB fully contiguous (8 cache lines).

// ---------------- kernel 1: heterogeneous pre-pass ----------------
__global__ __launch_bounds__(256)
void k_pre(const float* __restrict__ x, const float* __restrict__ W,
           const float* __restrict__ att_src, const float* __restrict__ att_dst,
           const float* __restrict__ adj,
           unsigned short* __restrict__ hpt, float* __restrict__ ast,
           float* __restrict__ adt, unsigned* __restrict__ abits)
{
    const int t = threadIdx.x;
    if (blockIdx.x < HPB) {
        __shared__ alignas(16) float    xs[8 * F_IN];
        __shared__ alignas(16) unsigned hs[F_IN * 4];
        __shared__ float ssa[4][8], ssd[4][8];
        const int sub = t >> 7;
        const int tt  = t & 127;
        const int i0  = blockIdx.x * 8;
        reinterpret_cast<float4*>(xs)[t] =
            reinterpret_cast<const float4*>(x + (size_t)i0 * F_IN)[t];
        __syncthreads();

        const float4* W4  = reinterpret_cast<const float4*>(W + tt * F_IN);
        const float4* xs4 = reinterpret_cast<const float4*>(xs + sub * 4 * F_IN);
        float a0 = 0.f, a1 = 0.f, a2 = 0.f, a3 = 0.f;
#pragma unroll
        for (int k = 0; k < F_IN / 4; ++k) {
            const float4 w  = W4[k];
            const float4 v0 = xs4[k], v1 = xs4[32 + k], v2 = xs4[64 + k], v3 = xs4[96 + k];
            a0 = fmaf(w.x, v0.x, a0); a0 = fmaf(w.y, v0.y, a0); a0 = fmaf(w.z, v0.z, a0); a0 = fmaf(w.w, v0.w, a0);
            a1 = fmaf(w.x, v1.x, a1); a1 = fmaf(w.y, v1.y, a1); a1 = fmaf(w.z, v1.z, a1); a1 = fmaf(w.w, v1.w, a1);
            a2 = fmaf(w.x, v2.x, a2); a2 = fmaf(w.y, v2.y, a2); a2 = fmaf(w.z, v2.z, a2); a2 = fmaf(w.w, v2.w, a2);
            a3 = fmaf(w.x, v3.x, a3); a3 = fmaf(w.y, v3.y, a3); a3 = fmaf(w.z, v3.z, a3); a3 = fmaf(w.w, v3.w, a3);
        }
        hs[tt * 4 + sub * 2 + 0] = f2bfu(a0) | (f2bfu(a1) << 16);
        hs[tt * 4 + sub * 2 + 1] = f2bfu(a2) | (f2bfu(a3) << 16);

        const float asv = att_src[tt], adv = att_dst[tt];
        float s0 = a0 * asv, s1 = a1 * asv, s2 = a2 * asv, s3 = a3 * asv;
        float d0 = a0 * adv, d1 = a1 * adv, d2 = a2 * adv, d3 = a3 * adv;
#pragma unroll
        for (int s = 16; s; s >>= 1) {
            s0 += __shfl_xor(s0, s); s1 += __shfl_xor(s1, s);
            s2 += __shfl_xor(s2, s); s3 += __shfl_xor(s3, s);
            d0 += __shfl_xor(d0, s); d1 += __shfl_xor(d1, s);
            d2 += __shfl_xor(d2, s); d3 += __shfl_xor(d3, s);
        }
        if ((tt & 31) == 0) {
            const int hh = tt >> 5;
            ssa[hh][sub * 4 + 0] = s0 * L2E; ssa[hh][sub * 4 + 1] = s1 * L2E;
            ssa[hh][sub * 4 + 2] = s2 * L2E; ssa[hh][sub * 4 + 3] = s3 * L2E;
            ssd[hh][sub * 4 + 0] = d0 * L2E; ssd[hh][sub * 4 + 1] = d1 * L2E;
            ssd[hh][sub * 4 + 2] = d2 * L2E; ssd[hh][sub * 4 + 3] = d3 * L2E;
        }
        __syncthreads();
        if (t < 128)   // tiled layout: ((i0>>4)*128 + f)*16 + (i0&15)
            *reinterpret_cast<uint4*>(
                hpt + ((size_t)(i0 >> 4) * 128 + t) * 16 + (i0 & 15)) =
                *reinterpret_cast<const uint4*>(&hs[t * 4]);
        if (t < 64) {
            const int sd = t >> 5, hh = (t >> 3) & 3, nn = t & 7;
            const float v = sd ? ssd[hh][nn] : ssa[hh][nn];
            (sd ? adt : ast)[hh * N_NODES + i0 + nn] = v;
        }
    } else {
        __shared__ alignas(16) unsigned short lb[64 * 16];
        const int sblk  = blockIdx.x - HPB;
        const int strip = sblk & 63;
        const int chunk = sblk >> 6;
        const int c0    = strip * 64;
        const int r0    = chunk * 256;
        const int q     = t & 15;
        const int p     = t >> 4;
        const float4* adj4 = reinterpret_cast<const float4*>(adj);

        float4 v[16];
#pragma unroll
        for (int it = 0; it < 16; ++it)
            v[it] = adj4[(size_t)(r0 + p * 16 + it) * (N_NODES / 4) + (c0 >> 2) + q];
        unsigned mk0 = 0, mk1 = 0, mk2 = 0, mk3 = 0;
#pragma unroll
        for (int it = 0; it < 16; ++it) {
            mk0 |= (v[it].x != 0.f) ? (1u << it) : 0u;
            mk1 |= (v[it].y != 0.f) ? (1u << it) : 0u;
            mk2 |= (v[it].z != 0.f) ? (1u << it) : 0u;
            mk3 |= (v[it].w != 0.f) ? (1u << it) : 0u;
        }
        lb[(4 * q + 0) * 16 + p] = (unsigned short)mk0;
        lb[(4 * q + 1) * 16 + p] = (unsigned short)mk1;
        lb[(4 * q + 2) * 16 + p] = (unsigned short)mk2;
        lb[(4 * q + 3) * 16 + p] = (unsigned short)mk3;
        __syncthreads();
        const unsigned* lb32 = reinterpret_cast<const unsigned*>(lb);
#pragma unroll
        for (int j = 0; j < 2; ++j) {
            const int w = t + j * 256;
            const int m = w >> 3, col = w & 7;
            abits[(size_t)(c0 + m) * (N_NODES / 32) + chunk * 8 + col] = lb32[w];
        }
    }
}

// ---------------- kernel 2: fused MFMA (r15 arithmetic + coalesced access) ----------------
// 1024 blocks (4/CU): 32 m x 4 waves (wave=head) x 512-n split.
// B-frags: 1KB contiguous per wave from tiled hpt. e: ds_read_b128 pairs.
__global__ __launch_bounds__(256, 4)
void k_main(const unsigned short* __restrict__ hpt, const float* __restrict__ ast,
            const float* __restrict__ adt, const unsigned* __restrict__ abits,
            unsigned short* __restrict__ zp16, float* __restrict__ taup)
{
    __shared__ alignas(16) float2 ea_s[HEADS * NRANGE];   // 16 KB
    const int t     = threadIdx.x;
    const int wv    = t >> 6;                  // head
    const int l     = t & 63;
    const int np    = l >> 5;
    const int lm    = l & 31;
    const int mt    = blockIdx.x >> 3;
    const int split = blockIdx.x & 7;
    const int m0    = mt * 32;
    const int nb0   = split * NRANGE;

    // stage EA tables (verified r12/r15)
#pragma unroll
    for (int j = 0; j < 8; ++j) {
        const int lin = j * 256 + t;           // 0..2047
        const int h   = lin >> 9;
        const int n   = lin & 511;
        const float a = ast[h * N_NODES + nb0 + n];
        ea_s[lin] = make_float2(__builtin_amdgcn_exp2f(a),
                                __builtin_amdgcn_exp2f(0.2f * a));
    }
    // adjacency bits (verified r12)
    uint4 brow[4];
    {
        const uint4* bsrc = reinterpret_cast<const uint4*>(
            abits + (size_t)(m0 + lm) * (N_NODES / 32) + split * 16);
#pragma unroll
        for (int j = 0; j < 4; ++j) brow[j] = bsrc[j];
    }
    const float adm = adt[wv * N_NODES + m0 + lm];
    const float ed1 = __builtin_amdgcn_exp2f(adm);
    const float ed2 = __builtin_amdgcn_exp2f(0.2f * adm);
    __syncthreads();

    // tiled hpt: lane's slot within an n-block = (wv*32+lm)*16 + np*8
    const unsigned short* hbase = hpt + ((size_t)(nb0 >> 4) * 128 + wv * 32 + lm) * 16 + np * 8;
    const float2* eaw = ea_s + wv * NRANGE;

    float16v acc;
#pragma unroll
    for (int r = 0; r < 16; ++r) acc[r] = 0.f;
    float tau = 0.f;

#pragma unroll
    for (int step = 0; step < NSTEP; ++step) {
#pragma unroll
        for (int q = 0; q < 4; ++q) {
            const int nq = step * 64 + q * 16;
            const short8v bv = *reinterpret_cast<const short8v*>(
                hbase + (size_t)(step * 4 + q) * 2048);   // 2048 shorts per n-block
            // e: 4 x ds_read_b128 (pairs of float2), 128B-aligned base
            const float4* ea4 = reinterpret_cast<const float4*>(eaw + nq) + np * 4;
            float4 ep0 = ea4[0], ep1 = ea4[1], ep2 = ea4[2], ep3 = ea4[3];
            const unsigned w32 = (&brow[0].x)[(step * 2 + (q >> 1)) & 15];
            const unsigned bb  = (w32 >> (((q & 1) << 4) + (np << 3))) & 0xFFu;
            float w[8];
            w[0] = (bb & 1u)   ? fmaxf(ep0.x * ed1, ep0.y * ed2) : 0.f;
            w[1] = (bb & 2u)   ? fmaxf(ep0.z * ed1, ep0.w * ed2) : 0.f;
            w[2] = (bb & 4u)   ? fmaxf(ep1.x * ed1, ep1.y * ed2) : 0.f;
            w[3] = (bb & 8u)   ? fmaxf(ep1.z * ed1, ep1.w * ed2) : 0.f;
            w[4] = (bb & 16u)  ? fmaxf(ep2.x * ed1, ep2.y * ed2) : 0.f;
            w[5] = (bb & 32u)  ? fmaxf(ep2.z * ed1, ep2.w * ed2) : 0.f;
            w[6] = (bb & 64u)  ? fmaxf(ep3.x * ed1, ep3.y * ed2) : 0.f;
            w[7] = (bb & 128u) ? fmaxf(ep3.z * ed1, ep3.w * ed2) : 0.f;
            tau += ((w[0] + w[1]) + (w[2] + w[3])) + ((w[4] + w[5]) + (w[6] + w[7]));
            union { short8v v; unsigned u[4]; } af;
            af.u[0] = cvt_pk_bf16(w[0], w[1]);
            af.u[1] = cvt_pk_bf16(w[2], w[3]);
            af.u[2] = cvt_pk_bf16(w[4], w[5]);
            af.u[3] = cvt_pk_bf16(w[6], w[7]);
            acc = __builtin_amdgcn_mfma_f32_32x32x16_bf16(af.v, bv, acc, 0, 0, 0);
        }
    }

    // epilogue (verified r12-15)
    tau += __shfl_xor(tau, 32);
    if (np == 0)
        taup[((size_t)split * HEADS + wv) * N_NODES + m0 + lm] = tau;
    unsigned short* zp = zp16 + (size_t)split * N_NODES * FTOT;
#pragma unroll
    for (int r = 0; r < 16; ++r) {
        const int row = (r & 3) + 8 * (r >> 2) + 4 * np;
        zp[(size_t)(m0 + row) * FTOT + wv * 32 + lm] = (unsigned short)f2bfu(acc[r]);
    }
}

// ---------------- kernel 3: merge 8 bf16 splits, divide by tau, add bias ----------------
__global__ __launch_bounds__(256)
void k_fin(const unsigned* __restrict__ zp32, const float* __restrict__ taup,
           const float* __restrict__ bias, float* __restrict__ out)
{
    const int idx = blockIdx.x * 256 + threadIdx.x;  // over N*FTOT/4 quads
    const int m = idx >> 5, f4 = idx & 31, h = f4 >> 3;
    float4 z = make_float4(0.f, 0.f, 0.f, 0.f);
    float ts = 0.f;
#pragma unroll
    for (int s = 0; s < NSPLIT; ++s) {
        const uint2 u = reinterpret_cast<const uint2*>(zp32)[(size_t)s * (N_NODES * FTOT / 4) + idx];
        z.x += __uint_as_float(u.x << 16);
        z.y += __uint_as_float(u.x & 0xffff0000u);
        z.z += __uint_as_float(u.y << 16);
        z.w += __uint_as_float(u.y & 0xffff0000u);
        ts += taup[((size_t)s * HEADS + h) * N_NODES + m];
    }
    const float inv = 1.f / ts;
    const float4 b = reinterpret_cast<const float4*>(bias)[f4];
    float4 o;
    o.x = z.x * inv + b.x; o.y = z.y * inv + b.y;
    o.z = z.z * inv + b.z; o.w = z.w * inv + b.w;
    reinterpret_cast<float4*>(out)[idx] = o;
}

extern "C" void kernel_launch(void* const* d_in, const int* in_sizes, int n_in,
                              void* d_out, int out_size, void* d_ws, size_t ws_size,
                              hipStream_t stream) {
    const float* x       = (const float*)d_in[0];
    const float* adj     = (const float*)d_in[1];
    const float* weight  = (const float*)d_in[2];
    const float* att_src = (const float*)d_in[3];
    const float* att_dst = (const float*)d_in[4];
    const float* bias    = (const float*)d_in[5];
    float* out = (float*)d_out;

    // ws: hpt 1MB | ast 64KB | adt 64KB | abits 2MB | zp16 8MB | taup 512KB
    unsigned short* hpt = (unsigned short*)d_ws;
    float* ast = (float*)(hpt + (size_t)FTOT * N_NODES);
    float* adt = ast + (size_t)HEADS * N_NODES;
    unsigned* abits = (unsigned*)(adt + (size_t)HEADS * N_NODES);
    unsigned short* zp16 = (unsigned short*)(abits + (size_t)N_NODES * (N_NODES / 32));
    float* taup = (float*)(zp16 + (size_t)NSPLIT * N_NODES * FTOT);

    k_pre <<<HPB + BITB, 256, 0, stream>>>(x, weight, att_src, att_dst, adj,
                                           hpt, ast, adt, abits);
    k_main<<<(N_NODES / 32) * NSPLIT, 256, 0, stream>>>(hpt, ast, adt, abits,
                                                        zp16, taup);
    k_fin <<<N_NODES * (FTOT / 4) / 256, 256, 0, stream>>>((const unsigned*)zp16,
                                                           taup, bias, out);
}

// Round 19
// 44.470 us; speedup vs baseline: 1.9829x; 1.9829x over previous
//
#include <hip/hip_runtime.h>
#include <hip/hip_bf16.h>

#define N_NODES 4096
#define F_IN    128
#define HEADS   4
#define FTOT    128
#define NSPLIT  8
#define NRANGE  (N_NODES / NSPLIT)   // 512
#define NSTEP   (NRANGE / 64)        // 8
#define HPB     512
#define BITB    1024
#define L2E     1.4426950408889634f

typedef __attribute__((ext_vector_type(8)))  short  short8v;
typedef __attribute__((ext_vector_type(16))) float  float16v;

static __device__ __forceinline__ unsigned f2bfu(float f) {
    union { __hip_bfloat16 h; unsigned short u; } cv;
    cv.h = __float2bfloat16(f);
    return (unsigned)cv.u;
}
static __device__ __forceinline__ unsigned cvt_pk_bf16(float lo, float hi) {
    unsigned r;
    asm("v_cvt_pk_bf16_f32 %0, %1, %2" : "=v"(r) : "v"(lo), "v"(hi));
    return r;
}

// ---------------- kernel 1: heterogeneous pre-pass (r15, verified) ----------------
__global__ __launch_bounds__(256)
void k_pre(const float* __restrict__ x, const float* __restrict__ W,
           const float* __restrict__ att_src, const float* __restrict__ att_dst,
           const float* __restrict__ adj,
           unsigned short* __restrict__ hpt, float* __restrict__ ast,
           float* __restrict__ adt, unsigned* __restrict__ abits)
{
    const int t = threadIdx.x;
    if (blockIdx.x < HPB) {
        __shared__ alignas(16) float    xs[8 * F_IN];
        __shared__ alignas(16) unsigned hs[F_IN * 4];
        __shared__ float ssa[4][8], ssd[4][8];
        const int sub = t >> 7;
        const int tt  = t & 127;
        const int i0  = blockIdx.x * 8;
        reinterpret_cast<float4*>(xs)[t] =
            reinterpret_cast<const float4*>(x + (size_t)i0 * F_IN)[t];
        __syncthreads();

        const float4* W4  = reinterpret_cast<const float4*>(W + tt * F_IN);
        const float4* xs4 = reinterpret_cast<const float4*>(xs + sub * 4 * F_IN);
        float a0 = 0.f, a1 = 0.f, a2 = 0.f, a3 = 0.f;
#pragma unroll
        for (int k = 0; k < F_IN / 4; ++k) {
            const float4 w  = W4[k];
            const float4 v0 = xs4[k], v1 = xs4[32 + k], v2 = xs4[64 + k], v3 = xs4[96 + k];
            a0 = fmaf(w.x, v0.x, a0); a0 = fmaf(w.y, v0.y, a0); a0 = fmaf(w.z, v0.z, a0); a0 = fmaf(w.w, v0.w, a0);
            a1 = fmaf(w.x, v1.x, a1); a1 = fmaf(w.y, v1.y, a1); a1 = fmaf(w.z, v1.z, a1); a1 = fmaf(w.w, v1.w, a1);
            a2 = fmaf(w.x, v2.x, a2); a2 = fmaf(w.y, v2.y, a2); a2 = fmaf(w.z, v2.z, a2); a2 = fmaf(w.w, v2.w, a2);
            a3 = fmaf(w.x, v3.x, a3); a3 = fmaf(w.y, v3.y, a3); a3 = fmaf(w.z, v3.z, a3); a3 = fmaf(w.w, v3.w, a3);
        }
        hs[tt * 4 + sub * 2 + 0] = f2bfu(a0) | (f2bfu(a1) << 16);
        hs[tt * 4 + sub * 2 + 1] = f2bfu(a2) | (f2bfu(a3) << 16);

        const float asv = att_src[tt], adv = att_dst[tt];
        float s0 = a0 * asv, s1 = a1 * asv, s2 = a2 * asv, s3 = a3 * asv;
        float d0 = a0 * adv, d1 = a1 * adv, d2 = a2 * adv, d3 = a3 * adv;
#pragma unroll
        for (int s = 16; s; s >>= 1) {
            s0 += __shfl_xor(s0, s); s1 += __shfl_xor(s1, s);
            s2 += __shfl_xor(s2, s); s3 += __shfl_xor(s3, s);
            d0 += __shfl_xor(d0, s); d1 += __shfl_xor(d1, s);
            d2 += __shfl_xor(d2, s); d3 += __shfl_xor(d3, s);
        }
        if ((tt & 31) == 0) {
            const int hh = tt >> 5;
            ssa[hh][sub * 4 + 0] = s0 * L2E; ssa[hh][sub * 4 + 1] = s1 * L2E;
            ssa[hh][sub * 4 + 2] = s2 * L2E; ssa[hh][sub * 4 + 3] = s3 * L2E;
            ssd[hh][sub * 4 + 0] = d0 * L2E; ssd[hh][sub * 4 + 1] = d1 * L2E;
            ssd[hh][sub * 4 + 2] = d2 * L2E; ssd[hh][sub * 4 + 3] = d3 * L2E;
        }
        __syncthreads();
        if (t < 128)
            *reinterpret_cast<uint4*>(hpt + (size_t)t * N_NODES + i0) =
                *reinterpret_cast<const uint4*>(&hs[t * 4]);
        if (t < 64) {
            const int sd = t >> 5, hh = (t >> 3) & 3, nn = t & 7;
            const float v = sd ? ssd[hh][nn] : ssa[hh][nn];
            (sd ? adt : ast)[hh * N_NODES + i0 + nn] = v;
        }
    } else {
        __shared__ alignas(16) unsigned short lb[64 * 16];
        const int sblk  = blockIdx.x - HPB;
        const int strip = sblk & 63;
        const int chunk = sblk >> 6;
        const int c0    = strip * 64;
        const int r0    = chunk * 256;
        const int q     = t & 15;
        const int p     = t >> 4;
        const float4* adj4 = reinterpret_cast<const float4*>(adj);

        float4 v[16];
#pragma unroll
        for (int it = 0; it < 16; ++it)
            v[it] = adj4[(size_t)(r0 + p * 16 + it) * (N_NODES / 4) + (c0 >> 2) + q];
        unsigned mk0 = 0, mk1 = 0, mk2 = 0, mk3 = 0;
#pragma unroll
        for (int it = 0; it < 16; ++it) {
            mk0 |= (v[it].x != 0.f) ? (1u << it) : 0u;
            mk1 |= (v[it].y != 0.f) ? (1u << it) : 0u;
            mk2 |= (v[it].z != 0.f) ? (1u << it) : 0u;
            mk3 |= (v[it].w != 0.f) ? (1u << it) : 0u;
        }
        lb[(4 * q + 0) * 16 + p] = (unsigned short)mk0;
        lb[(4 * q + 1) * 16 + p] = (unsigned short)mk1;
        lb[(4 * q + 2) * 16 + p] = (unsigned short)mk2;
        lb[(4 * q + 3) * 16 + p] = (unsigned short)mk3;
        __syncthreads();
        const unsigned* lb32 = reinterpret_cast<const unsigned*>(lb);
#pragma unroll
        for (int j = 0; j < 2; ++j) {
            const int w = t + j * 256;
            const int m = w >> 3, col = w & 7;
            abits[(size_t)(c0 + m) * (N_NODES / 32) + chunk * 8 + col] = lb32[w];
        }
    }
}

// ---------------- kernel 2: fused MFMA, 512-thread blocks (2 m-subtiles x 4 heads) ----------------
// 512 blocks (2/CU): 64 m x 8 waves x 512-n split. Per-wave code is r15's
// verified loop verbatim with m0 = mt*64 + (wv>>2)*32. Halves hpt re-read
// traffic and ea-staging cost per m; 2 waves/head share hpt lines in L1.
__global__ __launch_bounds__(512, 4)
void k_main(const unsigned short* __restrict__ hpt, const float* __restrict__ ast,
            const float* __restrict__ adt, const unsigned* __restrict__ abits,
            unsigned short* __restrict__ zp16, float* __restrict__ taup)
{
    __shared__ alignas(16) float2 ea_s[HEADS * NRANGE];   // 16 KB
    const int t     = threadIdx.x;
    const int wvid  = t >> 6;                  // 0..7
    const int wv    = wvid & 3;                // head
    const int msub  = wvid >> 2;               // m-subtile 0/1
    const int l     = t & 63;
    const int np    = l >> 5;
    const int lm    = l & 31;
    const int mt    = blockIdx.x >> 3;
    const int split = blockIdx.x & 7;          // bid%8 = split -> per-XCD slice locality
    const int m0    = mt * 64 + msub * 32;
    const int nb0   = split * NRANGE;

    // stage EA tables (verified r12/r15), 512 threads x 4
#pragma unroll
    for (int j = 0; j < 4; ++j) {
        const int lin = j * 512 + t;           // 0..2047
        const int h   = lin >> 9;
        const int n   = lin & 511;
        const float a = ast[h * N_NODES + nb0 + n];
        ea_s[lin] = make_float2(__builtin_amdgcn_exp2f(a),
                                __builtin_amdgcn_exp2f(0.2f * a));
    }
    // adjacency bits for this lane's m-row (verified r12)
    uint4 brow[4];
    {
        const uint4* bsrc = reinterpret_cast<const uint4*>(
            abits + (size_t)(m0 + lm) * (N_NODES / 32) + split * 16);
#pragma unroll
        for (int j = 0; j < 4; ++j) brow[j] = bsrc[j];
    }
    const float adm = adt[wv * N_NODES + m0 + lm];
    const float ed1 = __builtin_amdgcn_exp2f(adm);
    const float ed2 = __builtin_amdgcn_exp2f(0.2f * adm);
    __syncthreads();

    const unsigned short* hrow = hpt + (size_t)(wv * 32 + lm) * N_NODES + nb0 + np * 8;
    const float2* eaw = ea_s + wv * NRANGE;

    float16v acc;
#pragma unroll
    for (int r = 0; r < 16; ++r) acc[r] = 0.f;
    float tau = 0.f;

#pragma unroll
    for (int step = 0; step < NSTEP; ++step) {
#pragma unroll
        for (int q = 0; q < 4; ++q) {
            const int nq = step * 64 + q * 16;
            const short8v bv = *reinterpret_cast<const short8v*>(hrow + nq);
            const float2* eap = eaw + nq + np * 8;
            const unsigned w32 = (&brow[0].x)[(step * 2 + (q >> 1)) & 15];
            const unsigned bb  = (w32 >> (((q & 1) << 4) + (np << 3))) & 0xFFu;
            float w[8];
#pragma unroll
            for (int i = 0; i < 8; ++i) {
                const float2 e = eap[i];
                const float sel = fmaxf(e.x * ed1, e.y * ed2);
                w[i] = (bb & (1u << i)) ? sel : 0.f;
            }
            tau += ((w[0] + w[1]) + (w[2] + w[3])) + ((w[4] + w[5]) + (w[6] + w[7]));
            union { short8v v; unsigned u[4]; } af;
            af.u[0] = cvt_pk_bf16(w[0], w[1]);
            af.u[1] = cvt_pk_bf16(w[2], w[3]);
            af.u[2] = cvt_pk_bf16(w[4], w[5]);
            af.u[3] = cvt_pk_bf16(w[6], w[7]);
            acc = __builtin_amdgcn_mfma_f32_32x32x16_bf16(af.v, bv, acc, 0, 0, 0);
        }
    }

    // epilogue (verified r12-15)
    tau += __shfl_xor(tau, 32);
    if (np == 0)
        taup[((size_t)split * HEADS + wv) * N_NODES + m0 + lm] = tau;
    unsigned short* zp = zp16 + (size_t)split * N_NODES * FTOT;
#pragma unroll
    for (int r = 0; r < 16; ++r) {
        const int row = (r & 3) + 8 * (r >> 2) + 4 * np;
        zp[(size_t)(m0 + row) * FTOT + wv * 32 + lm] = (unsigned short)f2bfu(acc[r]);
    }
}

// ---------------- kernel 3: merge 8 bf16 splits, divide by tau, add bias ----------------
__global__ __launch_bounds__(256)
void k_fin(const unsigned* __restrict__ zp32, const float* __restrict__ taup,
           const float* __restrict__ bias, float* __restrict__ out)
{
    const int idx = blockIdx.x * 256 + threadIdx.x;  // over N*FTOT/4 quads
    const int m = idx >> 5, f4 = idx & 31, h = f4 >> 3;
    float4 z = make_float4(0.f, 0.f, 0.f, 0.f);
    float ts = 0.f;
#pragma unroll
    for (int s = 0; s < NSPLIT; ++s) {
        const uint2 u = reinterpret_cast<const uint2*>(zp32)[(size_t)s * (N_NODES * FTOT / 4) + idx];
        z.x += __uint_as_float(u.x << 16);
        z.y += __uint_as_float(u.x & 0xffff0000u);
        z.z += __uint_as_float(u.y << 16);
        z.w += __uint_as_float(u.y & 0xffff0000u);
        ts += taup[((size_t)s * HEADS + h) * N_NODES + m];
    }
    const float inv = 1.f / ts;
    const float4 b = reinterpret_cast<const float4*>(bias)[f4];
    float4 o;
    o.x = z.x * inv + b.x; o.y = z.y * inv + b.y;
    o.z = z.z * inv + b.z; o.w = z.w * inv + b.w;
    reinterpret_cast<float4*>(out)[idx] = o;
}

extern "C" void kernel_launch(void* const* d_in, const int* in_sizes, int n_in,
                              void* d_out, int out_size, void* d_ws, size_t ws_size,
                              hipStream_t stream) {
    const float* x       = (const float*)d_in[0];
    const float* adj     = (const float*)d_in[1];
    const float* weight  = (const float*)d_in[2];
    const float* att_src = (const float*)d_in[3];
    const float* att_dst = (const float*)d_in[4];
    const float* bias    = (const float*)d_in[5];
    float* out = (float*)d_out;

    // ws: hpt 1MB | ast 64KB | adt 64KB | abits 2MB | zp16 8MB | taup 512KB
    unsigned short* hpt = (unsigned short*)d_ws;
    float* ast = (float*)(hpt + (size_t)FTOT * N_NODES);
    float* adt = ast + (size_t)HEADS * N_NODES;
    unsigned* abits = (unsigned*)(adt + (size_t)HEADS * N_NODES);
    unsigned short* zp16 = (unsigned short*)(abits + (size_t)N_NODES * (N_NODES / 32));
    float* taup = (float*)(zp16 + (size_t)NSPLIT * N_NODES * FTOT);

    k_pre <<<HPB + BITB, 256, 0, stream>>>(x, weight, att_src, att_dst, adj,
                                           hpt, ast, adt, abits);
    k_main<<<(N_NODES / 64) * NSPLIT, 512, 0, stream>>>(hpt, ast, adt, abits,
                                                        zp16, taup);
    k_fin <<<N_NODES * (FTOT / 4) / 256, 256, 0, stream>>>((const unsigned*)zp16,
                                                           taup, bias, out);
}